// Round 5
// baseline (74.256 us; speedup 1.0000x reference)
//
#include <hip/hip_runtime.h>

// MeanAggregator: 4 fused gather outputs.
//   out0 = mean_k features[neigh_idx[b,k]]          [B, D]
//   out1 = mean_k features[perm[neigh_idx[b,k]]]    [B, D]
//   out2 = features[nodes[b]]                       [B, D]
//   out3 = features[perm[nodes[b]]]                 [B, D]
// B=16384, K=10, D=256, features [100000, 256] f32.
//
// R5: node-range PHASING on top of R4's XCD-affine D-slicing.
// R4 result: fabric/L2-miss-bound at ~5.8 TB/s; per-XCD sub-table is
// 12.8 MB vs 4 MB L2 (hit ~31%). Phase the gathers over P=4 node
// ranges (25000 rows = 3.2 MB/XCD per phase): all blocks sweep ranges
// in the same order, so re-reads within a phase stay L2-resident.
// Indices staged in LDS once, re-scanned each phase.

typedef float f32x4 __attribute__((ext_vector_type(4)));

constexpr int BATCH    = 16384;
constexpr int K_SAMPLE = 10;
constexpr int D_FEAT   = 256;
constexpr int N_NODES  = 100000;
constexpr int SLICES   = 8;                         // 32 dims (128 B) per slice
constexpr int SLICE_D  = D_FEAT / SLICES;           // 32 floats
constexpr int CHUNK    = 32;                        // batch rows per block
constexpr int THREADS  = 256;                       // 8 threads/row x 32 rows
constexpr int PHASES   = 4;
constexpr int RANGE    = N_NODES / PHASES;          // 25000 rows/phase

__global__ __launch_bounds__(THREADS)
void mean_agg_kernel(const float* __restrict__ features,
                     const int*   __restrict__ neigh_idx,
                     const int*   __restrict__ nodes,
                     const int*   __restrict__ perm,
                     float*       __restrict__ out)
{
    const int slice = blockIdx.x & (SLICES - 1);    // -> XCD id (round-robin)
    const int chunk = blockIdx.x >> 3;

    const int t     = threadIdx.x;
    const int g     = t >> 3;                       // row-in-chunk 0..31
    const int lane8 = t & 7;                        // float4 column in slice

    const int b = chunk * CHUNK + g;
    const int d = slice * SLICE_D + lane8 * 4;

    // ---- stage all indices (and perm lookups) for this chunk in LDS ----
    __shared__ int s_idx [CHUNK * K_SAMPLE];
    __shared__ int s_pidx[CHUNK * K_SAMPLE];
    __shared__ int s_n [CHUNK];
    __shared__ int s_pn[CHUNK];

    for (int i = t; i < CHUNK * K_SAMPLE; i += THREADS) {
        const int idx = neigh_idx[chunk * CHUNK * K_SAMPLE + i];
        s_idx [i] = idx;
        s_pidx[i] = perm[idx];
    }
    if (t < CHUNK) {
        const int n = nodes[chunk * CHUNK + t];
        s_n [t] = n;
        s_pn[t] = perm[n];
    }
    __syncthreads();

    f32x4 acc  = {0.f, 0.f, 0.f, 0.f};
    f32x4 accs = {0.f, 0.f, 0.f, 0.f};
    f32x4 o2   = {0.f, 0.f, 0.f, 0.f};
    f32x4 o3   = {0.f, 0.f, 0.f, 0.f};

    // ---- phase sweep over node ranges: gathers only fire when the row
    //      index falls in the current 3.2 MB/XCD window ----
    for (int p = 0; p < PHASES; ++p) {
        const int lo = p * RANGE;
        const int hi = lo + RANGE;

        #pragma unroll
        for (int k = 0; k < K_SAMPLE; ++k) {
            const int idx = s_idx[g * K_SAMPLE + k];        // group-uniform
            if (idx >= lo && idx < hi)
                acc += *reinterpret_cast<const f32x4*>(
                    &features[(size_t)idx * D_FEAT + d]);
            const int pidx = s_pidx[g * K_SAMPLE + k];
            if (pidx >= lo && pidx < hi)
                accs += *reinterpret_cast<const f32x4*>(
                    &features[(size_t)pidx * D_FEAT + d]);
        }
        const int n = s_n[g];
        if (n >= lo && n < hi)
            o2 = *reinterpret_cast<const f32x4*>(
                &features[(size_t)n * D_FEAT + d]);
        const int pn = s_pn[g];
        if (pn >= lo && pn < hi)
            o3 = *reinterpret_cast<const f32x4*>(
                &features[(size_t)pn * D_FEAT + d]);

        __syncthreads();   // keep the block's 4 waves phase-aligned
    }

    const float inv = 1.0f / (float)K_SAMPLE;
    const f32x4 o0 = acc  * inv;
    const f32x4 o1 = accs * inv;

    // ---- stores: outputs concatenated flat in return order ----
    const size_t row = (size_t)b * D_FEAT + d;
    const size_t sec = (size_t)BATCH * D_FEAT;
    __builtin_nontemporal_store(o0, reinterpret_cast<f32x4*>(&out[row]          ));
    __builtin_nontemporal_store(o1, reinterpret_cast<f32x4*>(&out[row +     sec]));
    __builtin_nontemporal_store(o2, reinterpret_cast<f32x4*>(&out[row + 2 * sec]));
    __builtin_nontemporal_store(o3, reinterpret_cast<f32x4*>(&out[row + 3 * sec]));
}

extern "C" void kernel_launch(void* const* d_in, const int* in_sizes, int n_in,
                              void* d_out, int out_size, void* d_ws, size_t ws_size,
                              hipStream_t stream) {
    const float* features  = (const float*)d_in[0];
    const int*   neigh_idx = (const int*)  d_in[1];
    const int*   nodes     = (const int*)  d_in[2];
    const int*   perm      = (const int*)  d_in[3];
    float*       out       = (float*)d_out;

    const int grid = (BATCH / CHUNK) * SLICES;      // 512 chunks x 8 slices = 4096
    mean_agg_kernel<<<grid, THREADS, 0, stream>>>(features, neigh_idx, nodes, perm, out);
}

// Round 6
// 67.431 us; speedup vs baseline: 1.1012x; 1.1012x over previous
//
#include <hip/hip_runtime.h>

// MeanAggregator: 4 fused gather outputs.
//   out0 = mean_k features[neigh_idx[b,k]]          [B, D]
//   out1 = mean_k features[perm[neigh_idx[b,k]]]    [B, D]
//   out2 = features[nodes[b]]                       [B, D]
//   out3 = features[perm[nodes[b]]]                 [B, D]
// B=16384, K=10, D=256, features [100000, 256] f32.
//
// R6: BUCKETED phasing. R5 proved phase-windowing cuts HBM fetch
// 137->89.5 MB, but predicated re-scan quadrupled VMEM issues and lost
// 14 us. Fix: per-(table,row) counting sort of the 10 indices into
// PHASES=4 buckets in LDS (one 64-thread pass), then each phase walks
// only its bucket -> issue count ~1.3x R4 instead of 4x, locality of R5.
// Keeps R4's XCD-affine D-slicing (slice = blockIdx%8) + NT stores.

typedef float f32x4 __attribute__((ext_vector_type(4)));

constexpr int BATCH    = 16384;
constexpr int K_SAMPLE = 10;
constexpr int D_FEAT   = 256;
constexpr int N_NODES  = 100000;
constexpr int SLICES   = 8;                 // 32 dims (128 B) per slice
constexpr int SLICE_D  = D_FEAT / SLICES;   // 32 floats
constexpr int CHUNK    = 32;                // batch rows per block
constexpr int THREADS  = 256;               // 8 threads/row x 32 rows
constexpr int PHASES   = 4;
constexpr int RANGE    = N_NODES / PHASES;  // 25000 rows -> 3.2 MB/XCD window

__global__ __launch_bounds__(THREADS)
void mean_agg_kernel(const float* __restrict__ features,
                     const int*   __restrict__ neigh_idx,
                     const int*   __restrict__ nodes,
                     const int*   __restrict__ perm,
                     float*       __restrict__ out)
{
    const int slice = blockIdx.x & (SLICES - 1);   // -> XCD id (round-robin)
    const int chunk = blockIdx.x >> 3;

    const int t     = threadIdx.x;
    const int g     = t >> 3;                      // row-in-chunk 0..31
    const int lane8 = t & 7;                       // float4 column in slice

    const int b = chunk * CHUNK + g;
    const int d = slice * SLICE_D + lane8 * 4;

    __shared__ int s_tmp [2][CHUNK * K_SAMPLE];    // raw idx / perm[idx]
    __shared__ int s_list[2][CHUNK][K_SAMPLE];     // phase-sorted idx
    __shared__ int s_off [2][CHUNK][PHASES + 1];   // bucket offsets
    __shared__ int s_n [CHUNK];
    __shared__ int s_pn[CHUNK];

    // ---- stage indices + perm lookups ----
    for (int i = t; i < CHUNK * K_SAMPLE; i += THREADS) {
        const int idx = neigh_idx[chunk * CHUNK * K_SAMPLE + i];
        s_tmp[0][i] = idx;
        s_tmp[1][i] = perm[idx];
    }
    if (t < CHUNK) {
        const int n = nodes[chunk * CHUNK + t];
        s_n [t] = n;
        s_pn[t] = perm[n];
    }
    __syncthreads();

    // ---- skip (self) gathers: unphased (2/22 of traffic), issued here so
    //      they are in flight while the sort runs ----
    const f32x4 o2 = *reinterpret_cast<const f32x4*>(
        &features[(size_t)s_n [g] * D_FEAT + d]);
    const f32x4 o3 = *reinterpret_cast<const f32x4*>(
        &features[(size_t)s_pn[g] * D_FEAT + d]);

    // ---- counting sort by phase: one worker per (table,row) = 64 threads ----
    if (t < 2 * CHUNK) {
        const int tb = t >> 5;                     // table 0..1
        const int r  = t & (CHUNK - 1);            // row 0..31
        int cnt[PHASES] = {0, 0, 0, 0};
        int ph[K_SAMPLE];
        #pragma unroll
        for (int k = 0; k < K_SAMPLE; ++k) {
            const int idx = s_tmp[tb][r * K_SAMPLE + k];
            const int p   = idx / RANGE;           // const-div -> mulhi+shift
            ph[k] = p;
            ++cnt[p];
        }
        int off = 0;
        #pragma unroll
        for (int p = 0; p < PHASES; ++p) {
            s_off[tb][r][p] = off;
            const int c = cnt[p];
            cnt[p] = off;
            off += c;
        }
        s_off[tb][r][PHASES] = off;                // == K_SAMPLE
        #pragma unroll
        for (int k = 0; k < K_SAMPLE; ++k)
            s_list[tb][r][cnt[ph[k]]++] = s_tmp[tb][r * K_SAMPLE + k];
    }
    __syncthreads();

    // ---- phase sweep: each group walks ONLY its bucket for this phase ----
    f32x4 acc  = {0.f, 0.f, 0.f, 0.f};
    f32x4 accs = {0.f, 0.f, 0.f, 0.f};

    for (int p = 0; p < PHASES; ++p) {
        const int e0 = s_off[0][g][p], e1 = s_off[0][g][p + 1];
        for (int j = e0; j < e1; ++j)
            acc += *reinterpret_cast<const f32x4*>(
                &features[(size_t)s_list[0][g][j] * D_FEAT + d]);
        const int f0 = s_off[1][g][p], f1 = s_off[1][g][p + 1];
        for (int j = f0; j < f1; ++j)
            accs += *reinterpret_cast<const f32x4*>(
                &features[(size_t)s_list[1][g][j] * D_FEAT + d]);
        __syncthreads();   // keep the block's waves phase-aligned
    }

    const float inv = 1.0f / (float)K_SAMPLE;
    const f32x4 o0 = acc  * inv;
    const f32x4 o1 = accs * inv;

    // ---- stores: outputs concatenated flat in return order ----
    const size_t row = (size_t)b * D_FEAT + d;
    const size_t sec = (size_t)BATCH * D_FEAT;
    __builtin_nontemporal_store(o0, reinterpret_cast<f32x4*>(&out[row]          ));
    __builtin_nontemporal_store(o1, reinterpret_cast<f32x4*>(&out[row +     sec]));
    __builtin_nontemporal_store(o2, reinterpret_cast<f32x4*>(&out[row + 2 * sec]));
    __builtin_nontemporal_store(o3, reinterpret_cast<f32x4*>(&out[row + 3 * sec]));
}

extern "C" void kernel_launch(void* const* d_in, const int* in_sizes, int n_in,
                              void* d_out, int out_size, void* d_ws, size_t ws_size,
                              hipStream_t stream) {
    const float* features  = (const float*)d_in[0];
    const int*   neigh_idx = (const int*)  d_in[1];
    const int*   nodes     = (const int*)  d_in[2];
    const int*   perm      = (const int*)  d_in[3];
    float*       out       = (float*)d_out;

    const int grid = (BATCH / CHUNK) * SLICES;     // 512 chunks x 8 slices = 4096
    mean_agg_kernel<<<grid, THREADS, 0, stream>>>(features, neigh_idx, nodes, perm, out);
}